// Round 1
// baseline (2881.972 us; speedup 1.0000x reference)
//
#include <hip/hip_runtime.h>
#include <stdint.h>

// ---------------- kernel 1: r[j] = 1/||emb_j|| ----------------
__global__ void inv_norms_kernel(const float* __restrict__ emb,
                                 float* __restrict__ r, int V, int E) {
    int row  = blockIdx.x * (blockDim.x >> 6) + (threadIdx.x >> 6);
    int lane = threadIdx.x & 63;
    if (row >= V) return;
    const float4* p = reinterpret_cast<const float4*>(emb + (size_t)row * E);
    float ss = 0.f;
    int n4 = E >> 2;
    for (int i = lane; i < n4; i += 64) {
        float4 v = p[i];
        ss = fmaf(v.x, v.x, ss);
        ss = fmaf(v.y, v.y, ss);
        ss = fmaf(v.z, v.z, ss);
        ss = fmaf(v.w, v.w, ss);
    }
    #pragma unroll
    for (int o = 32; o > 0; o >>= 1) ss += __shfl_down(ss, o, 64);
    if (lane == 0) r[row] = 1.0f / sqrtf(ss);
}

// ---------------- kernel 2: init packed keys ----------------
__global__ void init_keys_kernel(unsigned long long* __restrict__ keys, int M) {
    int i = blockIdx.x * blockDim.x + threadIdx.x;
    if (i < M) keys[i] = 0ULL;   // ordered(-inf) == 0
}

// ---------------- kernel 3: fused GEMM + argmax ----------------
#define BM 128
#define BN 128
#define BK 32
#define LDSPAD 4   // keeps float4 alignment (132*4 B stride), varies bank with k

__global__ __launch_bounds__(256) void nn_gemm_argmax(
    const float* __restrict__ batch, const float* __restrict__ emb,
    const float* __restrict__ rinv, unsigned long long* __restrict__ keys,
    int M, int V, int E)
{
    __shared__ float As[BK][BM + LDSPAD];
    __shared__ float Bs[BK][BN + LDSPAD];

    const int tid = threadIdx.x;
    const int tx  = tid & 15;   // col group: cols tx*8 .. +7
    const int ty  = tid >> 4;   // row group: rows ty*8 .. +7
    const int mb  = blockIdx.y;
    const int nb  = blockIdx.x;
    const int row0 = mb * BM;
    const int col0 = nb * BN;

    float acc[8][8];
    #pragma unroll
    for (int i = 0; i < 8; ++i)
        #pragma unroll
        for (int j = 0; j < 8; ++j) acc[i][j] = 0.f;

    const int steps = E / BK;
    for (int ks = 0; ks < steps; ++ks) {
        const int k0 = ks * BK;
        // A tile: BM x BK = 4096 floats -> 1024 float4, 4 per thread
        #pragma unroll
        for (int it = 0; it < 4; ++it) {
            int idx = it * 256 + tid;
            int rr  = idx >> 3;   // 0..127
            int cc  = idx & 7;    // float4 index in K
            float4 v = *reinterpret_cast<const float4*>(
                &batch[(size_t)(row0 + rr) * E + k0 + cc * 4]);
            As[cc * 4 + 0][rr] = v.x;
            As[cc * 4 + 1][rr] = v.y;
            As[cc * 4 + 2][rr] = v.z;
            As[cc * 4 + 3][rr] = v.w;
        }
        // B tile: BN x BK (emb rows are candidates)
        #pragma unroll
        for (int it = 0; it < 4; ++it) {
            int idx = it * 256 + tid;
            int rr  = idx >> 3;
            int cc  = idx & 7;
            int j   = col0 + rr;
            float4 v = make_float4(0.f, 0.f, 0.f, 0.f);
            if (j < V)
                v = *reinterpret_cast<const float4*>(
                    &emb[(size_t)j * E + k0 + cc * 4]);
            Bs[cc * 4 + 0][rr] = v.x;
            Bs[cc * 4 + 1][rr] = v.y;
            Bs[cc * 4 + 2][rr] = v.z;
            Bs[cc * 4 + 3][rr] = v.w;
        }
        __syncthreads();

        #pragma unroll
        for (int k = 0; k < BK; ++k) {
            float4 a0 = *reinterpret_cast<const float4*>(&As[k][ty * 8]);
            float4 a1 = *reinterpret_cast<const float4*>(&As[k][ty * 8 + 4]);
            float4 b0 = *reinterpret_cast<const float4*>(&Bs[k][tx * 8]);
            float4 b1 = *reinterpret_cast<const float4*>(&Bs[k][tx * 8 + 4]);
            float a[8] = {a0.x, a0.y, a0.z, a0.w, a1.x, a1.y, a1.z, a1.w};
            float b[8] = {b0.x, b0.y, b0.z, b0.w, b1.x, b1.y, b1.z, b1.w};
            #pragma unroll
            for (int i = 0; i < 8; ++i)
                #pragma unroll
                for (int jj = 0; jj < 8; ++jj)
                    acc[i][jj] = fmaf(a[i], b[jj], acc[i][jj]);
        }
        __syncthreads();
    }

    // Epilogue: score = dot * rinv[j]; per-row argmax, packed-key reduction.
    // key = ordered(score) << 32 | ~j  => max key == max score, ties -> lowest j
    #pragma unroll
    for (int i = 0; i < 8; ++i) {
        const int q = row0 + ty * 8 + i;
        unsigned long long best = 0ULL;
        #pragma unroll
        for (int jj = 0; jj < 8; ++jj) {
            int j = col0 + tx * 8 + jj;
            if (j < V) {
                float s = acc[i][jj] * rinv[j];
                unsigned u = __float_as_uint(s);
                u = (u & 0x80000000u) ? ~u : (u | 0x80000000u);
                unsigned long long key =
                    ((unsigned long long)u << 32) | (unsigned)(~(unsigned)j);
                if (key > best) best = key;
            }
        }
        // reduce across the 16 lanes sharing this row group (contiguous lanes)
        #pragma unroll
        for (int o = 8; o > 0; o >>= 1) {
            unsigned long long other = __shfl_xor(best, o, 64);
            if (other > best) best = other;
        }
        if (tx == 0 && best != 0ULL) atomicMax(&keys[q], best);
    }
}

// ---------------- kernel 4: extract indices ----------------
__global__ void extract_kernel(const unsigned long long* __restrict__ keys,
                               int* __restrict__ out, int M) {
    int i = blockIdx.x * blockDim.x + threadIdx.x;
    if (i < M) out[i] = (int)(~(unsigned)(keys[i] & 0xFFFFFFFFULL));
}

extern "C" void kernel_launch(void* const* d_in, const int* in_sizes, int n_in,
                              void* d_out, int out_size, void* d_ws, size_t ws_size,
                              hipStream_t stream) {
    const float* batch = (const float*)d_in[0];  // [B,S,E] f32
    const float* emb   = (const float*)d_in[1];  // [V,E]   f32
    int* out = (int*)d_out;                      // [B,S] int32

    const int M = out_size;                 // B*S = 4096
    const int E = in_sizes[0] / M;          // 512
    const int V = in_sizes[1] / E;          // 50000

    float* rinv = (float*)d_ws;
    unsigned long long* keys =
        (unsigned long long*)((char*)d_ws + (((size_t)V * 4 + 7) & ~(size_t)7));

    inv_norms_kernel<<<(V + 3) / 4, 256, 0, stream>>>(emb, rinv, V, E);
    init_keys_kernel<<<(M + 255) / 256, 256, 0, stream>>>(keys, M);

    dim3 grid((V + BN - 1) / BN, M / BM);
    nn_gemm_argmax<<<grid, 256, 0, stream>>>(batch, emb, rinv, keys, M, V, E);

    extract_kernel<<<(M + 255) / 256, 256, 0, stream>>>(keys, out, M);
}

// Round 2
// 778.394 us; speedup vs baseline: 3.7025x; 3.7025x over previous
//
#include <hip/hip_runtime.h>
#include <stdint.h>

typedef _Float16 f16;
typedef _Float16 f16x4 __attribute__((ext_vector_type(4)));
typedef _Float16 f16x8 __attribute__((ext_vector_type(8)));
typedef float    f32x4 __attribute__((ext_vector_type(4)));

#define LO_SCALE 2048.0f
#define LO_INV   (1.0f / 2048.0f)

__device__ __forceinline__ void llds16(const void* g, void* l) {
    __builtin_amdgcn_global_load_lds(
        (const __attribute__((address_space(1))) void*)g,
        (__attribute__((address_space(3))) void*)l, 16, 0, 0);
}

__device__ __forceinline__ unsigned long long pack_key(float s, int j) {
    unsigned u = __float_as_uint(s);
    u = (u & 0x80000000u) ? ~u : (u | 0x80000000u);
    return ((unsigned long long)u << 32) | (unsigned)(~(unsigned)j);
}

// ---------------- convert emb -> hi/lo fp16 + rinv ----------------
__global__ void convert_emb_kernel(const float* __restrict__ emb,
                                   f16* __restrict__ bh, f16* __restrict__ bl,
                                   float* __restrict__ rinv, int V, int E) {
    int row  = blockIdx.x * (blockDim.x >> 6) + (threadIdx.x >> 6);
    int lane = threadIdx.x & 63;
    if (row >= V) return;
    const float4* p = (const float4*)(emb + (size_t)row * E);
    int n4 = E >> 2;
    float ss = 0.f;
    for (int i = lane; i < n4; i += 64) {
        float4 v = p[i];
        ss = fmaf(v.x, v.x, ss); ss = fmaf(v.y, v.y, ss);
        ss = fmaf(v.z, v.z, ss); ss = fmaf(v.w, v.w, ss);
    }
    #pragma unroll
    for (int o = 32; o > 0; o >>= 1) ss += __shfl_down(ss, o, 64);
    ss = __shfl(ss, 0, 64);
    if (lane == 0) rinv[row] = 1.0f / sqrtf(ss);

    for (int i = lane; i < n4; i += 64) {
        float4 v = p[i];
        f16x4 h, l;
        h.x = (f16)v.x; l.x = (f16)((v.x - (float)h.x) * LO_SCALE);
        h.y = (f16)v.y; l.y = (f16)((v.y - (float)h.y) * LO_SCALE);
        h.z = (f16)v.z; l.z = (f16)((v.z - (float)h.z) * LO_SCALE);
        h.w = (f16)v.w; l.w = (f16)((v.w - (float)h.w) * LO_SCALE);
        *(f16x4*)&bh[(size_t)row * E + i * 4] = h;
        *(f16x4*)&bl[(size_t)row * E + i * 4] = l;
    }
}

// ---------------- convert batch -> hi/lo fp16 ----------------
__global__ void convert_batch_kernel(const float* __restrict__ batch,
                                     f16* __restrict__ ah, f16* __restrict__ al,
                                     int M, int E) {
    int row  = blockIdx.x * (blockDim.x >> 6) + (threadIdx.x >> 6);
    int lane = threadIdx.x & 63;
    if (row >= M) return;
    const float4* p = (const float4*)(batch + (size_t)row * E);
    int n4 = E >> 2;
    for (int i = lane; i < n4; i += 64) {
        float4 v = p[i];
        f16x4 h, l;
        h.x = (f16)v.x; l.x = (f16)((v.x - (float)h.x) * LO_SCALE);
        h.y = (f16)v.y; l.y = (f16)((v.y - (float)h.y) * LO_SCALE);
        h.z = (f16)v.z; l.z = (f16)((v.z - (float)h.z) * LO_SCALE);
        h.w = (f16)v.w; l.w = (f16)((v.w - (float)h.w) * LO_SCALE);
        *(f16x4*)&ah[(size_t)row * E + i * 4] = h;
        *(f16x4*)&al[(size_t)row * E + i * 4] = l;
    }
}

// ---------------- init packed keys ----------------
__global__ void init_keys_kernel(unsigned long long* __restrict__ keys, int M) {
    int i = blockIdx.x * blockDim.x + threadIdx.x;
    if (i < M) keys[i] = 0ULL;
}

// ---------------- MFMA GEMM + fused argmax ----------------
#define BM 128
#define BN 128
#define BKH 64   // K halfs per step

__global__ __launch_bounds__(256, 2) void nn_mfma_kernel(
    const f16* __restrict__ Ah, const f16* __restrict__ Al,
    const f16* __restrict__ Bh, const f16* __restrict__ Bl,
    const float* __restrict__ rinv, unsigned long long* __restrict__ keys,
    int M, int V, int E)
{
    __shared__ f16 sAh[BM * BKH], sAl[BM * BKH], sBh[BM * BKH], sBl[BM * BKH];

    const int tid  = threadIdx.x;
    const int lane = tid & 63;
    const int w    = tid >> 6;      // wave 0..3
    const int wr   = w >> 1;        // wave row 0..1
    const int wc   = w & 1;         // wave col 0..1
    const int fr   = lane & 15;     // fragment row/col
    const int kg   = lane >> 4;     // k-group 0..3

    const int row0 = blockIdx.x * BM;   // M block
    const int col0 = blockIdx.y * BN;   // N (V) block

    // ---- staging addressing: lane -> (row within 8-row group, 16B slot) ----
    const int srow  = lane >> 3;                  // 0..7
    const int sslot = lane & 7;                   // phys 16B slot
    const int xslot = sslot ^ srow;               // pre-swizzled source slot
    int aoff[4], boff[4], ldof[4];
    #pragma unroll
    for (int it = 0; it < 4; ++it) {
        int rl = w * 32 + it * 8 + srow;          // 0..127
        aoff[it] = (row0 + rl) * E + xslot * 8;   // halfs
        int bj = col0 + rl; if (bj > V - 1) bj = V - 1;
        boff[it] = bj * E + xslot * 8;
        ldof[it] = (w * 32 + it * 8) * BKH;       // wave-uniform LDS base (halfs)
    }

    f32x4 acc[4][4], accx[4][4];
    #pragma unroll
    for (int m = 0; m < 4; ++m)
        #pragma unroll
        for (int n = 0; n < 4; ++n) {
            acc[m][n]  = (f32x4){0.f, 0.f, 0.f, 0.f};
            accx[m][n] = (f32x4){0.f, 0.f, 0.f, 0.f};
        }

    const int steps = E / BKH;
    for (int ks = 0; ks < steps; ++ks) {
        const int kadv = ks * BKH;
        #pragma unroll
        for (int it = 0; it < 4; ++it) {
            llds16(Ah + aoff[it] + kadv, sAh + ldof[it]);
            llds16(Al + aoff[it] + kadv, sAl + ldof[it]);
            llds16(Bh + boff[it] + kadv, sBh + ldof[it]);
            llds16(Bl + boff[it] + kadv, sBl + ldof[it]);
        }
        __syncthreads();

        #pragma unroll
        for (int ksub = 0; ksub < 2; ++ksub) {
            f16x8 ah[4], al[4], bh[4], bl[4];
            #pragma unroll
            for (int m = 0; m < 4; ++m) {
                int row = wr * 64 + m * 16 + fr;
                int off = row * BKH + (((ksub * 4 + kg) ^ (fr & 7)) << 3);
                ah[m] = *(const f16x8*)&sAh[off];
                al[m] = *(const f16x8*)&sAl[off];
            }
            #pragma unroll
            for (int n = 0; n < 4; ++n) {
                int col = wc * 64 + n * 16 + fr;
                int off = col * BKH + (((ksub * 4 + kg) ^ (fr & 7)) << 3);
                bh[n] = *(const f16x8*)&sBh[off];
                bl[n] = *(const f16x8*)&sBl[off];
            }
            #pragma unroll
            for (int m = 0; m < 4; ++m)
                #pragma unroll
                for (int n = 0; n < 4; ++n) {
                    acc[m][n]  = __builtin_amdgcn_mfma_f32_16x16x32_f16(ah[m], bh[n], acc[m][n],  0, 0, 0);
                    accx[m][n] = __builtin_amdgcn_mfma_f32_16x16x32_f16(ah[m], bl[n], accx[m][n], 0, 0, 0);
                    accx[m][n] = __builtin_amdgcn_mfma_f32_16x16x32_f16(al[m], bh[n], accx[m][n], 0, 0, 0);
                }
        }
        __syncthreads();
    }

    // ---- epilogue: score = (hh + cross/2048) * rinv[j]; argmax ----
    const int colb = col0 + wc * 64;
    float ri[4];
    #pragma unroll
    for (int n = 0; n < 4; ++n) {
        int j = colb + n * 16 + fr;
        ri[n] = (j < V) ? rinv[j] : 0.f;
    }
    #pragma unroll
    for (int m = 0; m < 4; ++m) {
        #pragma unroll
        for (int r = 0; r < 4; ++r) {
            unsigned long long best = 0ULL;
            #pragma unroll
            for (int n = 0; n < 4; ++n) {
                int j = colb + n * 16 + fr;
                if (j < V) {
                    float s = (acc[m][n][r] + accx[m][n][r] * LO_INV) * ri[n];
                    unsigned long long key = pack_key(s, j);
                    if (key > best) best = key;
                }
            }
            #pragma unroll
            for (int o = 8; o > 0; o >>= 1) {
                unsigned long long other = __shfl_xor(best, o, 64);
                if (other > best) best = other;
            }
            if (fr == 0 && best != 0ULL) {
                int row = row0 + wr * 64 + m * 16 + kg * 4 + r;
                atomicMax(&keys[row], best);
            }
        }
    }
}

// ---------------- extract indices ----------------
__global__ void extract_kernel(const unsigned long long* __restrict__ keys,
                               int* __restrict__ out, int M) {
    int i = blockIdx.x * blockDim.x + threadIdx.x;
    if (i < M) out[i] = (int)(~(unsigned)(keys[i] & 0xFFFFFFFFULL));
}

// ================= fallback fp32 path (round-0, validated) =================
__global__ void inv_norms_kernel(const float* __restrict__ emb,
                                 float* __restrict__ r, int V, int E) {
    int row  = blockIdx.x * (blockDim.x >> 6) + (threadIdx.x >> 6);
    int lane = threadIdx.x & 63;
    if (row >= V) return;
    const float4* p = reinterpret_cast<const float4*>(emb + (size_t)row * E);
    float ss = 0.f;
    int n4 = E >> 2;
    for (int i = lane; i < n4; i += 64) {
        float4 v = p[i];
        ss = fmaf(v.x, v.x, ss); ss = fmaf(v.y, v.y, ss);
        ss = fmaf(v.z, v.z, ss); ss = fmaf(v.w, v.w, ss);
    }
    #pragma unroll
    for (int o = 32; o > 0; o >>= 1) ss += __shfl_down(ss, o, 64);
    if (lane == 0) r[row] = 1.0f / sqrtf(ss);
}

#define FBM 128
#define FBN 128
#define FBK 32
#define LDSPAD 4

__global__ __launch_bounds__(256) void nn_gemm_argmax(
    const float* __restrict__ batch, const float* __restrict__ emb,
    const float* __restrict__ rinv, unsigned long long* __restrict__ keys,
    int M, int V, int E)
{
    __shared__ float As[FBK][FBM + LDSPAD];
    __shared__ float Bs[FBK][FBN + LDSPAD];
    const int tid = threadIdx.x;
    const int tx  = tid & 15;
    const int ty  = tid >> 4;
    const int row0 = blockIdx.y * FBM;
    const int col0 = blockIdx.x * FBN;
    float acc[8][8];
    #pragma unroll
    for (int i = 0; i < 8; ++i)
        #pragma unroll
        for (int j = 0; j < 8; ++j) acc[i][j] = 0.f;
    const int steps = E / FBK;
    for (int ks = 0; ks < steps; ++ks) {
        const int k0 = ks * FBK;
        #pragma unroll
        for (int it = 0; it < 4; ++it) {
            int idx = it * 256 + tid;
            int rr = idx >> 3, cc = idx & 7;
            float4 v = *reinterpret_cast<const float4*>(
                &batch[(size_t)(row0 + rr) * E + k0 + cc * 4]);
            As[cc*4+0][rr] = v.x; As[cc*4+1][rr] = v.y;
            As[cc*4+2][rr] = v.z; As[cc*4+3][rr] = v.w;
        }
        #pragma unroll
        for (int it = 0; it < 4; ++it) {
            int idx = it * 256 + tid;
            int rr = idx >> 3, cc = idx & 7;
            int j = col0 + rr;
            float4 v = make_float4(0.f,0.f,0.f,0.f);
            if (j < V)
                v = *reinterpret_cast<const float4*>(&emb[(size_t)j * E + k0 + cc * 4]);
            Bs[cc*4+0][rr] = v.x; Bs[cc*4+1][rr] = v.y;
            Bs[cc*4+2][rr] = v.z; Bs[cc*4+3][rr] = v.w;
        }
        __syncthreads();
        #pragma unroll
        for (int k = 0; k < FBK; ++k) {
            float4 a0 = *reinterpret_cast<const float4*>(&As[k][ty*8]);
            float4 a1 = *reinterpret_cast<const float4*>(&As[k][ty*8+4]);
            float4 b0 = *reinterpret_cast<const float4*>(&Bs[k][tx*8]);
            float4 b1 = *reinterpret_cast<const float4*>(&Bs[k][tx*8+4]);
            float a[8] = {a0.x,a0.y,a0.z,a0.w,a1.x,a1.y,a1.z,a1.w};
            float b[8] = {b0.x,b0.y,b0.z,b0.w,b1.x,b1.y,b1.z,b1.w};
            #pragma unroll
            for (int i = 0; i < 8; ++i)
                #pragma unroll
                for (int jj = 0; jj < 8; ++jj)
                    acc[i][jj] = fmaf(a[i], b[jj], acc[i][jj]);
        }
        __syncthreads();
    }
    #pragma unroll
    for (int i = 0; i < 8; ++i) {
        const int q = row0 + ty * 8 + i;
        unsigned long long best = 0ULL;
        #pragma unroll
        for (int jj = 0; jj < 8; ++jj) {
            int j = col0 + tx * 8 + jj;
            if (j < V) {
                unsigned long long key = pack_key(acc[i][jj] * rinv[j], j);
                if (key > best) best = key;
            }
        }
        #pragma unroll
        for (int o = 8; o > 0; o >>= 1) {
            unsigned long long other = __shfl_xor(best, o, 64);
            if (other > best) best = other;
        }
        if (tx == 0 && best != 0ULL) atomicMax(&keys[q], best);
    }
}

// ================= launch =================
extern "C" void kernel_launch(void* const* d_in, const int* in_sizes, int n_in,
                              void* d_out, int out_size, void* d_ws, size_t ws_size,
                              hipStream_t stream) {
    const float* batch = (const float*)d_in[0];  // [B,S,E] f32
    const float* emb   = (const float*)d_in[1];  // [V,E]   f32
    int* out = (int*)d_out;

    const int M = out_size;                 // 4096
    const int E = in_sizes[0] / M;          // 512
    const int V = in_sizes[1] / E;          // 50000

    auto al256 = [](size_t x) { return (x + 255) & ~(size_t)255; };
    size_t o_rinv = 0;
    size_t o_keys = al256(o_rinv + (size_t)V * 4);
    size_t o_Ah   = al256(o_keys + (size_t)M * 8);
    size_t o_Al   = al256(o_Ah + (size_t)M * E * 2);
    size_t o_Bh   = al256(o_Al + (size_t)M * E * 2);
    size_t o_Bl   = al256(o_Bh + (size_t)V * E * 2);
    size_t need   = al256(o_Bl + (size_t)V * E * 2);

    unsigned long long* keys = (unsigned long long*)((char*)d_ws + o_keys);
    float* rinv = (float*)((char*)d_ws + o_rinv);

    if (ws_size >= need && (E % BKH) == 0 && (M % BM) == 0 && (E % 4) == 0) {
        f16* Ah = (f16*)((char*)d_ws + o_Ah);
        f16* Al = (f16*)((char*)d_ws + o_Al);
        f16* Bh = (f16*)((char*)d_ws + o_Bh);
        f16* Bl = (f16*)((char*)d_ws + o_Bl);

        convert_emb_kernel<<<(V + 3) / 4, 256, 0, stream>>>(emb, Bh, Bl, rinv, V, E);
        convert_batch_kernel<<<(M + 3) / 4, 256, 0, stream>>>(batch, Ah, Al, M, E);
        init_keys_kernel<<<(M + 255) / 256, 256, 0, stream>>>(keys, M);

        dim3 grid(M / BM, (V + BN - 1) / BN);  // x = M blocks: consecutive blocks share B panel
        nn_mfma_kernel<<<grid, 256, 0, stream>>>(Ah, Al, Bh, Bl, rinv, keys, M, V, E);

        extract_kernel<<<(M + 255) / 256, 256, 0, stream>>>(keys, out, M);
    } else {
        inv_norms_kernel<<<(V + 3) / 4, 256, 0, stream>>>(emb, rinv, V, E);
        init_keys_kernel<<<(M + 255) / 256, 256, 0, stream>>>(keys, M);
        dim3 grid((V + FBN - 1) / FBN, M / FBM);
        nn_gemm_argmax<<<grid, 256, 0, stream>>>(batch, emb, rinv, keys, M, V, E);
        extract_kernel<<<(M + 255) / 256, 256, 0, stream>>>(keys, out, M);
    }
}